// Round 4
// baseline (211.586 us; speedup 1.0000x reference)
//
#include <hip/hip_runtime.h>

#define N 4096
#define D 256
#define MARGIN 0.3f
#define BIG 10000.0f

typedef __bf16  bf16x8   __attribute__((ext_vector_type(8)));
typedef float   floatx16 __attribute__((ext_vector_type(16)));
typedef unsigned short ushort_t;

__device__ inline unsigned short f2bf(float f) {      // RNE fp32 -> bf16
    unsigned u = __float_as_uint(f);
    u += 0x7FFF + ((u >> 16) & 1);
    return (unsigned short)(u >> 16);
}
__device__ inline float bf2f(unsigned short h) {
    return __uint_as_float(((unsigned)h) << 16);
}

__device__ inline void atomicMaxFloatPos(float* addr, float v) {
    atomicMax((int*)addr, __float_as_int(v));   // valid: all values >= 0
}
__device__ inline void atomicMinFloatPos(float* addr, float v) {
    atomicMin((int*)addr, __float_as_int(v));
}

// async 16B global -> LDS (wave-uniform LDS base + lane*16)
__device__ inline void gl_lds16(const void* g, void* l) {
    __builtin_amdgcn_global_load_lds(
        (const __attribute__((address_space(1))) unsigned int*)g,
        (__attribute__((address_space(3))) unsigned int*)l, 16, 0, 0);
}

__global__ __launch_bounds__(256) void init_kernel(float* ap, float* ang, float* anl,
                                                   int* hist, float* loss, int* cnt) {
    int i = blockIdx.x * 256 + threadIdx.x;
    if (i < N) { ap[i] = 0.0f; ang[i] = BIG; anl[i] = BIG; }
    if (i < 4) hist[i] = 0;
    if (i == 0) { *loss = 0.0f; *cnt = 0; }
}

// One wave per row: hi/lo bf16 split of x (once!), sq[i], label histogram.
__global__ __launch_bounds__(256) void prep_kernel(const float* __restrict__ x,
                                                   const int* __restrict__ tgt,
                                                   float* __restrict__ sq, int* hist,
                                                   ushort_t* __restrict__ Xh,
                                                   ushort_t* __restrict__ Xl) {
    int wave = threadIdx.x >> 6, lane = threadIdx.x & 63;
    int row = blockIdx.x * 4 + wave;
    const float4 v = *(const float4*)(x + (size_t)row * D + lane * 4);
    ushort4 h, l; float hf;
    h.x = f2bf(v.x); hf = bf2f(h.x); l.x = f2bf(v.x - hf);
    h.y = f2bf(v.y); hf = bf2f(h.y); l.y = f2bf(v.y - hf);
    h.z = f2bf(v.z); hf = bf2f(h.z); l.z = f2bf(v.z - hf);
    h.w = f2bf(v.w); hf = bf2f(h.w); l.w = f2bf(v.w - hf);
    *(ushort4*)&Xh[(size_t)row * D + lane * 4] = h;
    *(ushort4*)&Xl[(size_t)row * D + lane * 4] = l;
    float s = v.x * v.x + v.y * v.y + v.z * v.z + v.w * v.w;
    #pragma unroll
    for (int off = 32; off; off >>= 1) s += __shfl_down(s, off);
    if (lane == 0) {
        sq[row] = s;
        atomicAdd(&hist[tgt[row] & 3], 1);
    }
}

// 128x128 tile per 256-thread block; split-bf16 MFMA (hi*hi + hi*lo + lo*hi).
// BK=32. LDS tile row = 128 B = 8 chunks of 16 B: chunks 0-3 hi k-quarters,
// 4-7 lo; logical chunk c stored at physical chunk c ^ (row&7) (XOR swizzle,
// conflict-free b128 reads). Staged via global_load_lds width=16 (swizzle
// applied on the per-lane SOURCE address; LDS dest is base + lane*16).
#define LD_FRAG(tile, row, ch) \
    (*(const bf16x8*)&tile[((row) << 6) + ((((ch) ^ ((row) & 7))) << 3)])

__global__ __launch_bounds__(256) void dist_kernel(const ushort_t* __restrict__ Xh,
                                                   const ushort_t* __restrict__ Xl,
                                                   const int* __restrict__ tgt,
                                                   const float* __restrict__ sq,
                                                   float* __restrict__ dist,
                                                   float* ap, float* ang, float* anl) {
    constexpr int BK = 32;
    __shared__ ushort_t Atile[128 * 64];   // 16 KiB
    __shared__ ushort_t Btile[128 * 64];   // 16 KiB

    const int t    = threadIdx.x;
    const int wv   = t >> 6, lane = t & 63;
    const int wm   = (wv >> 1) * 64;
    const int wn   = (wv & 1) * 64;
    const int row0 = blockIdx.y * 128;
    const int col0 = blockIdx.x * 128;

    // Staging per-lane constants: chunk index ci = wv*256 + j*64 + lane
    //   -> r = wv*32 + j*8 + (lane>>3), p = lane&7, logical c = p ^ (r&7).
    const int rr = lane >> 3;              // 0..7
    const int cc = (lane & 7) ^ rr;        // logical chunk 0..7 (wave-invariant)
    const int co = (cc & 3) * 8;           // k-element offset within stage
    const ushort_t* __restrict__ srcA = (cc < 4) ? Xh : Xl;

    floatx16 acc[2][2];
    #pragma unroll
    for (int mt = 0; mt < 2; ++mt)
        #pragma unroll
        for (int nt = 0; nt < 2; ++nt)
            #pragma unroll
            for (int r = 0; r < 16; ++r) acc[mt][nt][r] = 0.0f;

    const int ar = lane & 31;
    const int kh = (lane >> 5) * 8;

    for (int k0 = 0; k0 < D; k0 += BK) {
        __syncthreads();                   // previous stage's reads complete
        #pragma unroll
        for (int j = 0; j < 4; ++j) {
            const int r = wv * 32 + j * 8 + rr;
            const size_t goffA = (size_t)(row0 + r) * D + k0 + co;
            const size_t goffB = (size_t)(col0 + r) * D + k0 + co;
            gl_lds16(srcA + goffA, &Atile[(wv * 256 + j * 64) * 8]);
            gl_lds16(srcA + goffB, &Btile[(wv * 256 + j * 64) * 8]);
        }
        __syncthreads();                   // staging complete

        #pragma unroll
        for (int kk = 0; kk < BK; kk += 16) {
            const int ch = (kk + kh) >> 3; // 0..3
            bf16x8 a0h = LD_FRAG(Atile, wm      + ar, ch);
            bf16x8 a0l = LD_FRAG(Atile, wm      + ar, ch + 4);
            bf16x8 a1h = LD_FRAG(Atile, wm + 32 + ar, ch);
            bf16x8 a1l = LD_FRAG(Atile, wm + 32 + ar, ch + 4);
            bf16x8 b0h = LD_FRAG(Btile, wn      + ar, ch);
            bf16x8 b0l = LD_FRAG(Btile, wn      + ar, ch + 4);
            bf16x8 b1h = LD_FRAG(Btile, wn + 32 + ar, ch);
            bf16x8 b1l = LD_FRAG(Btile, wn + 32 + ar, ch + 4);

            acc[0][0] = __builtin_amdgcn_mfma_f32_32x32x16_bf16(a0h, b0h, acc[0][0], 0, 0, 0);
            acc[0][0] = __builtin_amdgcn_mfma_f32_32x32x16_bf16(a0h, b0l, acc[0][0], 0, 0, 0);
            acc[0][0] = __builtin_amdgcn_mfma_f32_32x32x16_bf16(a0l, b0h, acc[0][0], 0, 0, 0);

            acc[0][1] = __builtin_amdgcn_mfma_f32_32x32x16_bf16(a0h, b1h, acc[0][1], 0, 0, 0);
            acc[0][1] = __builtin_amdgcn_mfma_f32_32x32x16_bf16(a0h, b1l, acc[0][1], 0, 0, 0);
            acc[0][1] = __builtin_amdgcn_mfma_f32_32x32x16_bf16(a0l, b1h, acc[0][1], 0, 0, 0);

            acc[1][0] = __builtin_amdgcn_mfma_f32_32x32x16_bf16(a1h, b0h, acc[1][0], 0, 0, 0);
            acc[1][0] = __builtin_amdgcn_mfma_f32_32x32x16_bf16(a1h, b0l, acc[1][0], 0, 0, 0);
            acc[1][0] = __builtin_amdgcn_mfma_f32_32x32x16_bf16(a1l, b0h, acc[1][0], 0, 0, 0);

            acc[1][1] = __builtin_amdgcn_mfma_f32_32x32x16_bf16(a1h, b1h, acc[1][1], 0, 0, 0);
            acc[1][1] = __builtin_amdgcn_mfma_f32_32x32x16_bf16(a1h, b1l, acc[1][1], 0, 0, 0);
            acc[1][1] = __builtin_amdgcn_mfma_f32_32x32x16_bf16(a1l, b1h, acc[1][1], 0, 0, 0);
        }
    }

    // Epilogue. C/D layout: col = lane&31, row = (r&3) + 8*(r>>2) + 4*(lane>>5).
    int   gcol[2], tc[2];
    float sqc[2];
    #pragma unroll
    for (int nt = 0; nt < 2; ++nt) {
        gcol[nt] = col0 + wn + nt * 32 + (lane & 31);
        sqc[nt]  = sq[gcol[nt]];
        tc[nt]   = tgt[gcol[nt]];
    }
    const int rl_base = 4 * (lane >> 5);

    #pragma unroll
    for (int mt = 0; mt < 2; ++mt) {
        #pragma unroll
        for (int r = 0; r < 16; ++r) {
            const int row_local = (r & 3) + 8 * (r >> 2) + rl_base;
            const int grow = row0 + wm + mt * 32 + row_local;
            const float sqi = sq[grow];
            const int   ti  = tgt[grow];
            float mx = 0.0f, mg = BIG, ml = BIG;
            #pragma unroll
            for (int nt = 0; nt < 2; ++nt) {
                float d2 = sqi + sqc[nt] - 2.0f * acc[mt][nt][r];
                float dv = sqrtf(fmaxf(d2, 0.0f));
                dist[(size_t)grow * N + gcol[nt]] = dv;
                if (tc[nt] == ti)      mx = fmaxf(mx, dv);
                else if (tc[nt] > ti)  mg = fminf(mg, dv);
                else                   ml = fminf(ml, dv);
            }
            #pragma unroll
            for (int off = 1; off < 32; off <<= 1) {
                mx = fmaxf(mx, __shfl_xor(mx, off));
                mg = fminf(mg, __shfl_xor(mg, off));
                ml = fminf(ml, __shfl_xor(ml, off));
            }
            if ((lane & 31) == 0) {
                atomicMaxFloatPos(&ap[grow], mx);
                atomicMinFloatPos(&ang[grow], mg);
                atomicMinFloatPos(&anl[grow], ml);
            }
        }
    }
}

__global__ __launch_bounds__(256) void finish_kernel(const float* __restrict__ ap,
                                                     const float* __restrict__ ang,
                                                     const float* __restrict__ anl,
                                                     const int* __restrict__ tgt,
                                                     const int* __restrict__ hist,
                                                     float* loss_acc, int* cnt_acc) {
    int i = blockIdx.x * 256 + threadIdx.x;
    float term = 0.0f; int c = 0;
    if (i < N) {
        term = fmaxf(ap[i] - fabsf(ang[i] - anl[i]) + MARGIN, 0.0f);
        c = (hist[tgt[i] & 3] == 1) ? 1 : 0;
    }
    #pragma unroll
    for (int off = 32; off; off >>= 1) {
        term += __shfl_down(term, off);
        c    += __shfl_down(c, off);
    }
    if ((threadIdx.x & 63) == 0) {
        atomicAdd(loss_acc, term);
        atomicAdd(cnt_acc, c);
    }
}

__global__ void write_kernel(const float* loss_acc, const int* cnt_acc, float* out) {
    out[0] = loss_acc[0] * (1.0f / N);
    out[1 + (size_t)N * N] = (float)cnt_acc[0];
}

extern "C" void kernel_launch(void* const* d_in, const int* in_sizes, int n_in,
                              void* d_out, int out_size, void* d_ws, size_t ws_size,
                              hipStream_t stream) {
    const float* x   = (const float*)d_in[0];
    const int*   tgt = (const int*)d_in[1];
    float* out = (float*)d_out;
    float* ws  = (float*)d_ws;

    float*    sq   = ws;
    float*    ap   = ws + 4096;
    float*    ang  = ws + 8192;
    float*    anl  = ws + 12288;
    int*      hist = (int*)(ws + 16384);
    float*    loss = ws + 16388;
    int*      cnt  = (int*)(ws + 16389);
    ushort_t* Xh   = (ushort_t*)(ws + 16392);            // 16B-aligned, 2 MB
    ushort_t* Xl   = (ushort_t*)(ws + 16392 + 524288);   // 2 MB

    init_kernel<<<16, 256, 0, stream>>>(ap, ang, anl, hist, loss, cnt);
    prep_kernel<<<N / 4, 256, 0, stream>>>(x, tgt, sq, hist, Xh, Xl);
    dim3 grid(N / 128, N / 128);
    dist_kernel<<<grid, 256, 0, stream>>>(Xh, Xl, tgt, sq, out + 1, ap, ang, anl);
    finish_kernel<<<16, 256, 0, stream>>>(ap, ang, anl, tgt, hist, loss, cnt);
    write_kernel<<<1, 1, 0, stream>>>(loss, cnt, out);
}

// Round 5
// 114.632 us; speedup vs baseline: 1.8458x; 1.8458x over previous
//
#include <hip/hip_runtime.h>

#define N 4096
#define D 256
#define MARGIN 0.3f
#define BIG 10000.0f

typedef _Float16 f16x8 __attribute__((ext_vector_type(8)));
typedef _Float16 f16x4 __attribute__((ext_vector_type(4)));
typedef float floatx16 __attribute__((ext_vector_type(16)));

__device__ inline void atomicMaxFloatPos(float* a, float v) {
    atomicMax((int*)a, __float_as_int(v));   // valid: all values >= 0
}
__device__ inline void atomicMinFloatPos(float* a, float v) {
    atomicMin((int*)a, __float_as_int(v));
}

// async 16B global -> LDS (wave-uniform LDS base + lane*16)
__device__ inline void gl_lds16(const void* g, void* l) {
    __builtin_amdgcn_global_load_lds(
        (const __attribute__((address_space(1))) unsigned int*)g,
        (__attribute__((address_space(3))) unsigned int*)l, 16, 0, 0);
}

// Wave per row: convert x -> fp16 Xf (RNE), sq from the CONVERTED values
// (so the Gram diagonal cancels exactly), init ap/ang/anl.
__global__ __launch_bounds__(256) void prep_kernel(const float* __restrict__ x,
                                                   float* __restrict__ sq,
                                                   _Float16* __restrict__ Xf,
                                                   float* ap, float* ang, float* anl) {
    const int wave = threadIdx.x >> 6, lane = threadIdx.x & 63;
    const int row = blockIdx.x * 4 + wave;
    const float4 v = *(const float4*)(x + (size_t)row * D + lane * 4);
    f16x4 h;
    h[0] = (_Float16)v.x; h[1] = (_Float16)v.y;
    h[2] = (_Float16)v.z; h[3] = (_Float16)v.w;
    *(f16x4*)(Xf + (size_t)row * D + lane * 4) = h;
    const float c0 = (float)h[0], c1 = (float)h[1], c2 = (float)h[2], c3 = (float)h[3];
    float s = c0 * c0 + c1 * c1 + c2 * c2 + c3 * c3;
    #pragma unroll
    for (int off = 32; off; off >>= 1) s += __shfl_down(s, off);
    if (lane == 0) sq[row] = s;
    if (threadIdx.x < 4) {
        const int i = blockIdx.x * 4 + threadIdx.x;
        ap[i] = 0.0f; ang[i] = BIG; anl[i] = BIG;
    }
}

// One wave (64 threads) per 64x64 output tile. Wave-private 16 KB LDS,
// NO barriers. K-loop: 4 stages of BK=64, staged via global_load_lds
// (8 x 1KB per operand, 128B-contiguous segments), manual vmcnt(0).
// LDS layout: row-major 64 rows x 64 fp16 (128 B row = all 32 banks),
// 16B quad q of row r stored at phys quad q ^ (r&7) (conflict-free b128).
// Epilogue: phase A computes d, coalesced global stores + swizzled LDS
// f32 tile; phase B: lane = row, serial reduce, 3 atomics. No shuffles.
__global__ __launch_bounds__(64) void dist_kernel(const _Float16* __restrict__ Xf,
                                                  const int* __restrict__ tgt,
                                                  const float* __restrict__ sq,
                                                  float* __restrict__ dist,
                                                  float* ap, float* ang, float* anl) {
    __shared__ _Float16 lds[8192];          // 16 KiB total
    _Float16* ldsA = lds;                   // 64 x 64 fp16 (8 KiB)
    _Float16* ldsB = lds + 4096;            // 64 x 64 fp16 (8 KiB)
    float*    ldsC = (float*)lds;           // epilogue: 64 x 64 f32 (16 KiB)

    const int lane = threadIdx.x;
    const int row0 = blockIdx.y * 64;
    const int col0 = blockIdx.x * 64;

    // DMA per-lane source constants: lane -> (row-in-8-group, phys quad p),
    // fetch logical quad q = p ^ (row&7) so frag reads are conflict-free.
    const int drow = lane >> 3;                    // 0..7
    const int q    = (lane & 7) ^ drow;            // logical quad 0..7

    floatx16 acc[2][2];
    #pragma unroll
    for (int mt = 0; mt < 2; ++mt)
        #pragma unroll
        for (int nt = 0; nt < 2; ++nt)
            #pragma unroll
            for (int r = 0; r < 16; ++r) acc[mt][nt][r] = 0.0f;

    const int m0 = lane & 31;
    const int m1 = 32 + m0;

    for (int s = 0; s < 4; ++s) {
        const int k0 = s * 64;
        // ensure prior stage's LDS reads retired before DMA overwrites
        __asm__ volatile("s_waitcnt lgkmcnt(0)" ::: "memory");
        #pragma unroll
        for (int d = 0; d < 8; ++d) {
            const int r = d * 8 + drow;
            gl_lds16(Xf + (size_t)(row0 + r) * D + k0 + q * 8, ldsA + d * 512);
            gl_lds16(Xf + (size_t)(col0 + r) * D + k0 + q * 8, ldsB + d * 512);
        }
        __asm__ volatile("s_waitcnt vmcnt(0)" ::: "memory");

        #pragma unroll
        for (int ks = 0; ks < 4; ++ks) {
            const int lq = ks * 2 + (lane >> 5);   // logical quad 0..7
            f16x8 a0 = *(const f16x8*)(ldsA + m0 * 64 + ((lq ^ (m0 & 7)) << 3));
            f16x8 a1 = *(const f16x8*)(ldsA + m1 * 64 + ((lq ^ (m1 & 7)) << 3));
            f16x8 b0 = *(const f16x8*)(ldsB + m0 * 64 + ((lq ^ (m0 & 7)) << 3));
            f16x8 b1 = *(const f16x8*)(ldsB + m1 * 64 + ((lq ^ (m1 & 7)) << 3));
            acc[0][0] = __builtin_amdgcn_mfma_f32_32x32x16_f16(a0, b0, acc[0][0], 0, 0, 0);
            acc[0][1] = __builtin_amdgcn_mfma_f32_32x32x16_f16(a0, b1, acc[0][1], 0, 0, 0);
            acc[1][0] = __builtin_amdgcn_mfma_f32_32x32x16_f16(a1, b0, acc[1][0], 0, 0, 0);
            acc[1][1] = __builtin_amdgcn_mfma_f32_32x32x16_f16(a1, b1, acc[1][1], 0, 0, 0);
        }
        __asm__ volatile("" ::: "memory");   // pin stage ordering
    }

    // ---- Epilogue phase A: d = sqrt(sqi + sqj - 2*dot); store global (coalesced
    // dwords) + swizzled LDS f32 tile. C/D layout: col = lane&31,
    // row = (r&3) + 8*(r>>2) + 4*(lane>>5).
    const int gc0 = col0 + m0, gc1 = col0 + 32 + m0;
    const float sqc0 = sq[gc0], sqc1 = sq[gc1];
    const int rl_base = 4 * (lane >> 5);

    #pragma unroll
    for (int mt = 0; mt < 2; ++mt) {
        #pragma unroll
        for (int r = 0; r < 16; ++r) {
            const int row_l = mt * 32 + (r & 3) + 8 * (r >> 2) + rl_base;
            const int grow  = row0 + row_l;
            const float sqi = sq[grow];
            const float d0 = sqrtf(fmaxf(sqi + sqc0 - 2.0f * acc[mt][0][r], 0.0f));
            const float d1 = sqrtf(fmaxf(sqi + sqc1 - 2.0f * acc[mt][1][r], 0.0f));
            dist[(size_t)grow * N + gc0] = d0;
            dist[(size_t)grow * N + gc1] = d1;
            const int sw = row_l & 15;
            ldsC[row_l * 64 + (((m0 >> 2) ^ sw) << 2) + (m0 & 3)] = d0;
            ldsC[row_l * 64 + ((((m0 + 32) >> 2) ^ sw) << 2) + (m0 & 3)] = d1;
        }
    }
    __asm__ volatile("s_waitcnt lgkmcnt(0)" ::: "memory");

    // ---- Phase B: lane = row, serial reduce over 64 cols, 3 atomics.
    const int grow = row0 + lane;
    const int ti   = tgt[grow];
    float mx = 0.0f, mg = BIG, ml = BIG;
    #pragma unroll
    for (int j = 0; j < 16; ++j) {
        const int4  t4 = *(const int4*)&tgt[col0 + j * 4];    // uniform addr
        const float4 d4 = *(const float4*)&ldsC[lane * 64 + ((j ^ (lane & 15)) << 2)];
        if (t4.x == ti) mx = fmaxf(mx, d4.x); else if (t4.x > ti) mg = fminf(mg, d4.x); else ml = fminf(ml, d4.x);
        if (t4.y == ti) mx = fmaxf(mx, d4.y); else if (t4.y > ti) mg = fminf(mg, d4.y); else ml = fminf(ml, d4.y);
        if (t4.z == ti) mx = fmaxf(mx, d4.z); else if (t4.z > ti) mg = fminf(mg, d4.z); else ml = fminf(ml, d4.z);
        if (t4.w == ti) mx = fmaxf(mx, d4.w); else if (t4.w > ti) mg = fminf(mg, d4.w); else ml = fminf(ml, d4.w);
    }
    atomicMaxFloatPos(&ap[grow], mx);
    atomicMinFloatPos(&ang[grow], mg);
    atomicMinFloatPos(&anl[grow], ml);
}

// One block: histogram (packed wave reduce), then loss/cnt, write outputs.
__global__ __launch_bounds__(1024) void finish_kernel(const float* __restrict__ ap,
                                                      const float* __restrict__ ang,
                                                      const float* __restrict__ anl,
                                                      const int* __restrict__ tgt,
                                                      float* __restrict__ out) {
    __shared__ int hist[4];
    __shared__ unsigned hsum[2][16];
    __shared__ float wsum[16];
    __shared__ int wcnt[16];
    const int tid = threadIdx.x, lane = tid & 63, wv = tid >> 6;

    const int4 t4 = *(const int4*)&tgt[tid * 4];
    int c[4] = {0, 0, 0, 0};
    c[t4.x & 3]++; c[t4.y & 3]++; c[t4.z & 3]++; c[t4.w & 3]++;
    unsigned p01 = (unsigned)c[0] | ((unsigned)c[1] << 16);
    unsigned p23 = (unsigned)c[2] | ((unsigned)c[3] << 16);
    #pragma unroll
    for (int off = 32; off; off >>= 1) {
        p01 += __shfl_down(p01, off);
        p23 += __shfl_down(p23, off);
    }
    if (lane == 0) { hsum[0][wv] = p01; hsum[1][wv] = p23; }
    __syncthreads();
    if (tid == 0) {
        unsigned a = 0, b = 0;
        for (int i = 0; i < 16; ++i) { a += hsum[0][i]; b += hsum[1][i]; }
        hist[0] = a & 0xFFFF; hist[1] = a >> 16;
        hist[2] = b & 0xFFFF; hist[3] = b >> 16;
    }
    __syncthreads();

    float term = 0.0f; int cc = 0;
    const int lab[4] = {t4.x & 3, t4.y & 3, t4.z & 3, t4.w & 3};
    #pragma unroll
    for (int j = 0; j < 4; ++j) {
        const int i = tid * 4 + j;
        term += fmaxf(ap[i] - fabsf(ang[i] - anl[i]) + MARGIN, 0.0f);
        cc += (hist[lab[j]] == 1) ? 1 : 0;
    }
    #pragma unroll
    for (int off = 32; off; off >>= 1) {
        term += __shfl_down(term, off);
        cc   += __shfl_down(cc, off);
    }
    if (lane == 0) { wsum[wv] = term; wcnt[wv] = cc; }
    __syncthreads();
    if (tid == 0) {
        float ls = 0.0f; int cs = 0;
        for (int i = 0; i < 16; ++i) { ls += wsum[i]; cs += wcnt[i]; }
        out[0] = ls * (1.0f / N);
        out[1 + (size_t)N * N] = (float)cs;
    }
}

extern "C" void kernel_launch(void* const* d_in, const int* in_sizes, int n_in,
                              void* d_out, int out_size, void* d_ws, size_t ws_size,
                              hipStream_t stream) {
    const float* x   = (const float*)d_in[0];
    const int*   tgt = (const int*)d_in[1];
    float* out = (float*)d_out;
    char*  ws  = (char*)d_ws;

    _Float16* Xf  = (_Float16*)ws;                    // 2 MiB, 16B-aligned
    float*    sq  = (float*)(ws + 2097152);
    float*    ap  = sq + 4096;
    float*    ang = sq + 8192;
    float*    anl = sq + 12288;

    prep_kernel<<<N / 4, 256, 0, stream>>>(x, sq, Xf, ap, ang, anl);
    dim3 grid(N / 64, N / 64);
    dist_kernel<<<grid, 64, 0, stream>>>(Xf, tgt, sq, out + 1, ap, ang, anl);
    finish_kernel<<<1, 1024, 0, stream>>>(ap, ang, anl, tgt, out);
}